// Round 7
// baseline (787.385 us; speedup 1.0000x reference)
//
#include <hip/hip_runtime.h>
#include <hip/hip_fp16.h>

// ---------- binned edge staging ----------
#define RANGE    512
#define RSH      9
#define CAP      17408          // mean E/NB=16327 + 8 sigma
#define T_TILE   4096           // edges per binpass block (256 thr x 16)
#define LPAD     17             // padded floats per node in LDS accumulator

__global__ void init_gcursor(int* __restrict__ gcursor, int NB) {
    int t = blockIdx.x * blockDim.x + threadIdx.x;
    if (t < NB) gcursor[t] = t * CAP;
}

__global__ __launch_bounds__(256) void binpass(const int* __restrict__ src,
                                               const int* __restrict__ dst, int E,
                                               int* __restrict__ gcursor,
                                               unsigned* __restrict__ pairbuf) {
    __shared__ unsigned sbuf[T_TILE];
    __shared__ unsigned char sbk[T_TILE];
    __shared__ int lcount[256], loff[256], lplace[256], gbase[256];
    int t = threadIdx.x;
    int base = blockIdx.x * T_TILE;
    int ecount = min(T_TILE, E - base);

    lcount[t] = 0;
    __syncthreads();

    unsigned pk[16];
    int bn[16];
#pragma unroll
    for (int k = 0; k < 16; ++k) {
        int i = base + t + k * 256;
        if (i < E) {
            int s = src[i], d = dst[i];
            bn[k] = d >> RSH;
            pk[k] = ((unsigned)s << RSH) | (unsigned)(d & (RANGE - 1));
            atomicAdd(&lcount[bn[k]], 1);
        } else bn[k] = -1;
    }
    __syncthreads();
    loff[t] = lcount[t];
    __syncthreads();
    for (int off = 1; off < 256; off <<= 1) {
        int u = (t >= off) ? loff[t - off] : 0;
        __syncthreads();
        loff[t] += u;
        __syncthreads();
    }
    int ex = loff[t] - lcount[t];
    __syncthreads();
    loff[t] = ex;
    lplace[t] = ex;
    if (lcount[t] > 0) gbase[t] = atomicAdd(&gcursor[t], lcount[t]);
    __syncthreads();
#pragma unroll
    for (int k = 0; k < 16; ++k) {
        if (bn[k] >= 0) {
            int pos = atomicAdd(&lplace[bn[k]], 1);
            sbuf[pos] = pk[k];
            sbk[pos] = (unsigned char)bn[k];
        }
    }
    __syncthreads();
    for (int i = t; i < ecount; i += 256) {
        int b = sbk[i];
        pairbuf[gbase[b] + (i - loff[b])] = sbuf[i];
    }
}

// ---------- per-bucket degree histogram -> dinv ----------

__global__ __launch_bounds__(512) void hist_dinv(const unsigned* __restrict__ pairbuf,
                                                 const int* __restrict__ gcursor, int N,
                                                 float* __restrict__ dinv) {
    __shared__ int lcnt[RANGE];
    int b = blockIdx.x, t = threadIdx.x;
    int cnt = gcursor[b] - b * CAP;
    const unsigned* pb = pairbuf + (size_t)b * CAP;
    lcnt[t] = 0;
    __syncthreads();
    for (int i = t; i < cnt; i += 512) atomicAdd(&lcnt[pb[i] & (RANGE - 1)], 1);
    __syncthreads();
    int node = b * RANGE + t;
    if (node < N) dinv[node] = rsqrtf((float)lcnt[t] + 1.0f);
}

// ---------- GEMM1: g1 = fp16((x @ W1) * dinv[row]) ----------

__global__ __launch_bounds__(256) void gemm1_kernel(const float* __restrict__ x,
                                                    const float* __restrict__ W1,
                                                    const float* __restrict__ dinv,
                                                    __half* __restrict__ g1, int N) {
    __shared__ float sx[16][132];
    __shared__ float sW[128][16];
    int t = threadIdx.x;
    for (int i = t; i < 128 * 16; i += 256) sW[i / 16][i % 16] = W1[i];
    int row0 = blockIdx.x * 16;
    for (int i = t; i < 16 * 128; i += 256) {
        int r = i / 128, c = i % 128;
        int gr = row0 + r;
        sx[r][c] = (gr < N) ? x[gr * 128 + c] : 0.0f;
    }
    __syncthreads();
    int r = t / 16, c = t % 16;
    float acc = 0.0f;
#pragma unroll
    for (int k = 0; k < 128; ++k) acc += sx[r][k] * sW[k][c];
    int gr = row0 + r;
    if (gr < N) g1[gr * 16 + c] = __float2half(acc * dinv[gr]);
}

// ---------- agg layer 1: LDS fp32 accumulate per bucket; epilogue bias+relu -> g2 fp16 ----------

__global__ __launch_bounds__(1024) void agg1_kernel(const unsigned* __restrict__ pairbuf,
                                                    const int* __restrict__ gcursor,
                                                    const __half* __restrict__ g1,
                                                    const float* __restrict__ dinv,
                                                    const float* __restrict__ b1,
                                                    __half* __restrict__ g2, int N) {
    __shared__ float acc[RANGE * LPAD];
    int b = blockIdx.x, t = threadIdx.x;
    int cnt = gcursor[b] - b * CAP;
    const unsigned* pb = pairbuf + (size_t)b * CAP;
    for (int i = t; i < RANGE * LPAD; i += 1024) acc[i] = 0.0f;
    __syncthreads();
    int q4 = (t & 3) * 4;
    for (int e = (t >> 2); e < cnt; e += 256) {
        unsigned p = pb[e];
        int dloc = p & (RANGE - 1);
        int s = (int)(p >> RSH);
        uint2 v = *reinterpret_cast<const uint2*>(g1 + s * 16 + q4);
        float2 f0 = __half22float2(*reinterpret_cast<__half2*>(&v.x));
        float2 f1 = __half22float2(*reinterpret_cast<__half2*>(&v.y));
        float* a = acc + dloc * LPAD + q4;
        atomicAdd(a + 0, f0.x);
        atomicAdd(a + 1, f0.y);
        atomicAdd(a + 2, f1.x);
        atomicAdd(a + 3, f1.y);
    }
    __syncthreads();
    // epilogue: thread t -> node n = t>>1, features f0..f0+7
    int n = t >> 1, f0 = (t & 1) * 8;
    int ng = b * RANGE + n;
    if (ng < N) {
        float di = dinv[ng];
        uint4 sv = *reinterpret_cast<const uint4*>(g1 + ng * 16 + f0);
        __half2* sh = reinterpret_cast<__half2*>(&sv);
        float o[8];
#pragma unroll
        for (int k = 0; k < 4; ++k) {
            float2 sf = __half22float2(sh[k]);
            float a0 = acc[n * LPAD + f0 + 2 * k];
            float a1 = acc[n * LPAD + f0 + 2 * k + 1];
            o[2 * k]     = fmaxf(di * (a0 + sf.x) + b1[f0 + 2 * k], 0.0f) * di;
            o[2 * k + 1] = fmaxf(di * (a1 + sf.y) + b1[f0 + 2 * k + 1], 0.0f) * di;
        }
        uint4 wv;
        __half2* wh = reinterpret_cast<__half2*>(&wv);
#pragma unroll
        for (int k = 0; k < 4; ++k) wh[k] = __floats2half2_rn(o[2 * k], o[2 * k + 1]);
        *reinterpret_cast<uint4*>(g2 + ng * 16 + f0) = wv;
    }
}

// ---------- agg layer 2: same accumulate; epilogue -> agg2 fp32 ----------

__global__ __launch_bounds__(1024) void agg2_kernel(const unsigned* __restrict__ pairbuf,
                                                    const int* __restrict__ gcursor,
                                                    const __half* __restrict__ g2,
                                                    const float* __restrict__ dinv,
                                                    float* __restrict__ aggout, int N) {
    __shared__ float acc[RANGE * LPAD];
    int b = blockIdx.x, t = threadIdx.x;
    int cnt = gcursor[b] - b * CAP;
    const unsigned* pb = pairbuf + (size_t)b * CAP;
    for (int i = t; i < RANGE * LPAD; i += 1024) acc[i] = 0.0f;
    __syncthreads();
    int q4 = (t & 3) * 4;
    for (int e = (t >> 2); e < cnt; e += 256) {
        unsigned p = pb[e];
        int dloc = p & (RANGE - 1);
        int s = (int)(p >> RSH);
        uint2 v = *reinterpret_cast<const uint2*>(g2 + s * 16 + q4);
        float2 f0 = __half22float2(*reinterpret_cast<__half2*>(&v.x));
        float2 f1 = __half22float2(*reinterpret_cast<__half2*>(&v.y));
        float* a = acc + dloc * LPAD + q4;
        atomicAdd(a + 0, f0.x);
        atomicAdd(a + 1, f0.y);
        atomicAdd(a + 2, f1.x);
        atomicAdd(a + 3, f1.y);
    }
    __syncthreads();
    int n = t >> 1, f0 = (t & 1) * 8;
    int ng = b * RANGE + n;
    if (ng < N) {
        float di = dinv[ng];
        uint4 sv = *reinterpret_cast<const uint4*>(g2 + ng * 16 + f0);
        __half2* sh = reinterpret_cast<__half2*>(&sv);
        float4 o0, o1;
        float2 s0 = __half22float2(sh[0]);
        float2 s1 = __half22float2(sh[1]);
        float2 s2 = __half22float2(sh[2]);
        float2 s3 = __half22float2(sh[3]);
        o0.x = di * (acc[n * LPAD + f0 + 0] + s0.x);
        o0.y = di * (acc[n * LPAD + f0 + 1] + s0.y);
        o0.z = di * (acc[n * LPAD + f0 + 2] + s1.x);
        o0.w = di * (acc[n * LPAD + f0 + 3] + s1.y);
        o1.x = di * (acc[n * LPAD + f0 + 4] + s2.x);
        o1.y = di * (acc[n * LPAD + f0 + 5] + s2.y);
        o1.z = di * (acc[n * LPAD + f0 + 6] + s3.x);
        o1.w = di * (acc[n * LPAD + f0 + 7] + s3.y);
        *reinterpret_cast<float4*>(aggout + ng * 16 + f0) = o0;
        *reinterpret_cast<float4*>(aggout + ng * 16 + f0 + 4) = o1;
    }
}

// ---------- GEMM2: out = agg2 @ W2 + b2 ----------

__global__ __launch_bounds__(256) void gemm2_kernel(const float* __restrict__ aggin,
                                                    const float* __restrict__ W2,
                                                    const float* __restrict__ b2,
                                                    float* __restrict__ out, int N) {
    __shared__ float sW[16 * 128];
    int t = threadIdx.x;
    for (int i = t; i < 2048; i += 256) sW[i] = W2[i];
    __syncthreads();
    int col = t & 127;
    int half = t >> 7;
    int row0 = blockIdx.x * 16 + half * 8;
    float bias = b2[col];
#pragma unroll
    for (int j = 0; j < 8; ++j) {
        int row = row0 + j;
        if (row >= N) return;
        float acc = bias;
#pragma unroll
        for (int k = 0; k < 16; ++k) acc += aggin[row * 16 + k] * sW[k * 128 + col];
        out[row * 128 + col] = acc;
    }
}

// ---------- launch ----------

extern "C" void kernel_launch(void* const* d_in, const int* in_sizes, int n_in,
                              void* d_out, int out_size, void* d_ws, size_t ws_size,
                              hipStream_t stream) {
    const float* x  = (const float*)d_in[0];
    const int*   ei = (const int*)d_in[1];
    const float* W1 = (const float*)d_in[2];
    const float* b1 = (const float*)d_in[3];
    const float* W2 = (const float*)d_in[4];
    const float* b2 = (const float*)d_in[5];
    float* out = (float*)d_out;

    const int N = in_sizes[0] / 128;
    const int E = in_sizes[1] / 2;
    const int* src = ei;
    const int* dst = ei + E;
    const int NB = (N + RANGE - 1) / RANGE;   // 196

    // ws (4B units): [pairbuf NB*CAP][gcursor NB][dinv N][aggbuf 16N f32][g1 8N][g2 8N]
    unsigned* pairbuf = (unsigned*)d_ws;
    int* gcursor = (int*)(pairbuf + (size_t)NB * CAP);
    float* dinv  = (float*)(gcursor + NB);
    float* aggbuf = dinv + N;
    __half* g1 = (__half*)(aggbuf + 16 * N);
    __half* g2 = g1 + 16 * N;

    const int B = 256;
    init_gcursor<<<1, B, 0, stream>>>(gcursor, NB);
    binpass<<<(E + T_TILE - 1) / T_TILE, B, 0, stream>>>(src, dst, E, gcursor, pairbuf);
    hist_dinv<<<NB, 512, 0, stream>>>(pairbuf, gcursor, N, dinv);
    gemm1_kernel<<<(N + 15) / 16, B, 0, stream>>>(x, W1, dinv, g1, N);
    agg1_kernel<<<NB, 1024, 0, stream>>>(pairbuf, gcursor, g1, dinv, b1, g2, N);
    agg2_kernel<<<NB, 1024, 0, stream>>>(pairbuf, gcursor, g2, dinv, aggbuf, N);
    gemm2_kernel<<<(N + 15) / 16, B, 0, stream>>>(aggbuf, W2, b2, out, N);
}

// Round 8
// 195.050 us; speedup vs baseline: 4.0368x; 4.0368x over previous
//
#include <hip/hip_runtime.h>
#include <hip/hip_fp16.h>

// ---------- binned CSR build ----------
#define RANGE    512
#define RSH      9
#define CAP      17408          // mean E/NB=16327 + 8 sigma
#define T_TILE   4096           // edges per binpass block (256 thr x 16)

__global__ void init_gcursor(int* __restrict__ gcursor, int NB) {
    int t = blockIdx.x * blockDim.x + threadIdx.x;
    if (t < NB) gcursor[t] = t * CAP;
}

__global__ __launch_bounds__(256) void binpass(const int* __restrict__ src,
                                               const int* __restrict__ dst, int E,
                                               int* __restrict__ gcursor,
                                               unsigned* __restrict__ pairbuf) {
    __shared__ unsigned sbuf[T_TILE];
    __shared__ unsigned char sbk[T_TILE];
    __shared__ int lcount[256], loff[256], lplace[256], gbase[256];
    int t = threadIdx.x;
    int base = blockIdx.x * T_TILE;
    int ecount = min(T_TILE, E - base);

    lcount[t] = 0;
    __syncthreads();

    unsigned pk[16];
    int bn[16];
#pragma unroll
    for (int k = 0; k < 16; ++k) {
        int i = base + t + k * 256;
        if (i < E) {
            int s = src[i], d = dst[i];
            bn[k] = d >> RSH;
            pk[k] = ((unsigned)s << RSH) | (unsigned)(d & (RANGE - 1));
            atomicAdd(&lcount[bn[k]], 1);
        } else bn[k] = -1;
    }
    __syncthreads();
    loff[t] = lcount[t];
    __syncthreads();
    for (int off = 1; off < 256; off <<= 1) {
        int u = (t >= off) ? loff[t - off] : 0;
        __syncthreads();
        loff[t] += u;
        __syncthreads();
    }
    int ex = loff[t] - lcount[t];
    __syncthreads();
    loff[t] = ex;
    lplace[t] = ex;
    if (lcount[t] > 0) gbase[t] = atomicAdd(&gcursor[t], lcount[t]);
    __syncthreads();
#pragma unroll
    for (int k = 0; k < 16; ++k) {
        if (bn[k] >= 0) {
            int pos = atomicAdd(&lplace[bn[k]], 1);
            sbuf[pos] = pk[k];
            sbk[pos] = (unsigned char)bn[k];
        }
    }
    __syncthreads();
    for (int i = t; i < ecount; i += 256) {
        int b = sbk[i];
        pairbuf[gbase[b] + (i - loff[b])] = sbuf[i];
    }
}

__global__ __launch_bounds__(256) void bucketscan(const int* __restrict__ gcursor, int NB,
                                                  int* __restrict__ bbase,
                                                  int* __restrict__ rowptr, int N) {
    __shared__ int sd[256];
    int t = threadIdx.x;
    int c = (t < NB) ? (gcursor[t] - t * CAP) : 0;
    sd[t] = c;
    __syncthreads();
    for (int off = 1; off < 256; off <<= 1) {
        int u = (t >= off) ? sd[t - off] : 0;
        __syncthreads();
        sd[t] += u;
        __syncthreads();
    }
    if (t < NB) bbase[t] = sd[t] - c;
    if (t == 255) { bbase[NB] = sd[255]; rowptr[N] = sd[255]; }
}

__global__ __launch_bounds__(512) void bucket_build(const unsigned* __restrict__ pairbuf,
                                                    const int* __restrict__ gcursor,
                                                    const int* __restrict__ bbase, int N,
                                                    int* __restrict__ rowptr,
                                                    float* __restrict__ dinv,
                                                    int* __restrict__ eidx) {
    __shared__ int lcnt[RANGE];
    __shared__ int lsc[RANGE];
    int b = blockIdx.x, t = threadIdx.x;
    int cnt = gcursor[b] - b * CAP;
    const unsigned* pb = pairbuf + (size_t)b * CAP;

    lcnt[t] = 0;
    __syncthreads();
    for (int i = t; i < cnt; i += 512) atomicAdd(&lcnt[pb[i] & (RANGE - 1)], 1);
    __syncthreads();
    lsc[t] = lcnt[t];
    __syncthreads();
    for (int off = 1; off < 512; off <<= 1) {
        int u = (t >= off) ? lsc[t - off] : 0;
        __syncthreads();
        lsc[t] += u;
        __syncthreads();
    }
    int ex = lsc[t] - lcnt[t];
    int gb = bbase[b];
    int node = b * RANGE + t;
    if (node < N) {
        rowptr[node] = gb + ex;
        dinv[node] = rsqrtf((float)lcnt[t] + 1.0f);
    }
    __syncthreads();
    lsc[t] = gb + ex;
    __syncthreads();
    for (int i = t; i < cnt; i += 512) {
        unsigned p = pb[i];
        int pos = atomicAdd(&lsc[p & (RANGE - 1)], 1);
        eidx[pos] = (int)(p >> RSH);
    }
}

// ---------------- GEMM1: g1 = fp16((x @ W1) * dinv[row]) ----------------

__global__ __launch_bounds__(256) void gemm1_kernel(const float* __restrict__ x,
                                                    const float* __restrict__ W1,
                                                    const float* __restrict__ dinv,
                                                    __half* __restrict__ g1, int N) {
    __shared__ float sx[16][132];
    __shared__ float sW[128][16];
    int t = threadIdx.x;
    for (int i = t; i < 128 * 16; i += 256) sW[i / 16][i % 16] = W1[i];
    int row0 = blockIdx.x * 16;
    for (int i = t; i < 16 * 128; i += 256) {
        int r = i / 128, c = i % 128;
        int gr = row0 + r;
        sx[r][c] = (gr < N) ? x[gr * 128 + c] : 0.0f;
    }
    __syncthreads();
    int r = t / 16, c = t % 16;
    float acc = 0.0f;
#pragma unroll
    for (int k = 0; k < 128; ++k) acc += sx[r][k] * sW[k][c];
    int gr = row0 + r;
    if (gr < N) g1[gr * 16 + c] = __float2half(acc * dinv[gr]);
}

// ---------------- gather1: lane = (node, quarter); 16 consecutive nodes/wave ----------------

__global__ __launch_bounds__(256) void gather1_kernel(const int* __restrict__ rowptr,
                                                      const int* __restrict__ eidx,
                                                      const __half* __restrict__ g1,
                                                      const float* __restrict__ dinv,
                                                      const float* __restrict__ b1,
                                                      __half* __restrict__ g2, int N) {
    int gid = blockIdx.x * blockDim.x + threadIdx.x;
    int lane = threadIdx.x & 63;
    int q = lane & 3;
    int d = gid >> 2;              // node = (wave*16 + lane>>2)
    if (d >= N) return;
    int lo = rowptr[d], hi = rowptr[d + 1];
    float a0 = 0, a1 = 0, a2 = 0, a3 = 0;
    int j = lo;
    for (; j + 3 < hi; j += 4) {
        int s0 = eidx[j], s1 = eidx[j + 1], s2 = eidx[j + 2], s3 = eidx[j + 3];
        uint2 v0 = *reinterpret_cast<const uint2*>(g1 + s0 * 16 + q * 4);
        uint2 v1 = *reinterpret_cast<const uint2*>(g1 + s1 * 16 + q * 4);
        uint2 v2 = *reinterpret_cast<const uint2*>(g1 + s2 * 16 + q * 4);
        uint2 v3 = *reinterpret_cast<const uint2*>(g1 + s3 * 16 + q * 4);
        float2 p0 = __half22float2(*reinterpret_cast<__half2*>(&v0.x));
        float2 p1 = __half22float2(*reinterpret_cast<__half2*>(&v0.y));
        a0 += p0.x; a1 += p0.y; a2 += p1.x; a3 += p1.y;
        p0 = __half22float2(*reinterpret_cast<__half2*>(&v1.x));
        p1 = __half22float2(*reinterpret_cast<__half2*>(&v1.y));
        a0 += p0.x; a1 += p0.y; a2 += p1.x; a3 += p1.y;
        p0 = __half22float2(*reinterpret_cast<__half2*>(&v2.x));
        p1 = __half22float2(*reinterpret_cast<__half2*>(&v2.y));
        a0 += p0.x; a1 += p0.y; a2 += p1.x; a3 += p1.y;
        p0 = __half22float2(*reinterpret_cast<__half2*>(&v3.x));
        p1 = __half22float2(*reinterpret_cast<__half2*>(&v3.y));
        a0 += p0.x; a1 += p0.y; a2 += p1.x; a3 += p1.y;
    }
    for (; j < hi; ++j) {
        int s = eidx[j];
        uint2 v = *reinterpret_cast<const uint2*>(g1 + s * 16 + q * 4);
        float2 p0 = __half22float2(*reinterpret_cast<__half2*>(&v.x));
        float2 p1 = __half22float2(*reinterpret_cast<__half2*>(&v.y));
        a0 += p0.x; a1 += p0.y; a2 += p1.x; a3 += p1.y;
    }
    float di = dinv[d];
    uint2 sv = *reinterpret_cast<const uint2*>(g1 + d * 16 + q * 4);
    float2 sf0 = __half22float2(*reinterpret_cast<__half2*>(&sv.x));
    float2 sf1 = __half22float2(*reinterpret_cast<__half2*>(&sv.y));
    float4 bb = *reinterpret_cast<const float4*>(b1 + q * 4);
    float o0 = fmaxf(di * (a0 + sf0.x) + bb.x, 0.0f) * di;
    float o1 = fmaxf(di * (a1 + sf0.y) + bb.y, 0.0f) * di;
    float o2 = fmaxf(di * (a2 + sf1.x) + bb.z, 0.0f) * di;
    float o3 = fmaxf(di * (a3 + sf1.y) + bb.w, 0.0f) * di;
    __half2 w0 = __floats2half2_rn(o0, o1);
    __half2 w1 = __floats2half2_rn(o2, o3);
    uint2 wv;
    wv.x = *reinterpret_cast<unsigned*>(&w0);
    wv.y = *reinterpret_cast<unsigned*>(&w1);
    *reinterpret_cast<uint2*>(g2 + d * 16 + q * 4) = wv;
}

// ---------------- gather2: same structure, fp32 out ----------------

__global__ __launch_bounds__(256) void gather2_kernel(const int* __restrict__ rowptr,
                                                      const int* __restrict__ eidx,
                                                      const __half* __restrict__ g2,
                                                      const float* __restrict__ dinv,
                                                      float* __restrict__ agg2, int N) {
    int gid = blockIdx.x * blockDim.x + threadIdx.x;
    int lane = threadIdx.x & 63;
    int q = lane & 3;
    int d = gid >> 2;
    if (d >= N) return;
    int lo = rowptr[d], hi = rowptr[d + 1];
    float a0 = 0, a1 = 0, a2 = 0, a3 = 0;
    int j = lo;
    for (; j + 3 < hi; j += 4) {
        int s0 = eidx[j], s1 = eidx[j + 1], s2 = eidx[j + 2], s3 = eidx[j + 3];
        uint2 v0 = *reinterpret_cast<const uint2*>(g2 + s0 * 16 + q * 4);
        uint2 v1 = *reinterpret_cast<const uint2*>(g2 + s1 * 16 + q * 4);
        uint2 v2 = *reinterpret_cast<const uint2*>(g2 + s2 * 16 + q * 4);
        uint2 v3 = *reinterpret_cast<const uint2*>(g2 + s3 * 16 + q * 4);
        float2 p0 = __half22float2(*reinterpret_cast<__half2*>(&v0.x));
        float2 p1 = __half22float2(*reinterpret_cast<__half2*>(&v0.y));
        a0 += p0.x; a1 += p0.y; a2 += p1.x; a3 += p1.y;
        p0 = __half22float2(*reinterpret_cast<__half2*>(&v1.x));
        p1 = __half22float2(*reinterpret_cast<__half2*>(&v1.y));
        a0 += p0.x; a1 += p0.y; a2 += p1.x; a3 += p1.y;
        p0 = __half22float2(*reinterpret_cast<__half2*>(&v2.x));
        p1 = __half22float2(*reinterpret_cast<__half2*>(&v2.y));
        a0 += p0.x; a1 += p0.y; a2 += p1.x; a3 += p1.y;
        p0 = __half22float2(*reinterpret_cast<__half2*>(&v3.x));
        p1 = __half22float2(*reinterpret_cast<__half2*>(&v3.y));
        a0 += p0.x; a1 += p0.y; a2 += p1.x; a3 += p1.y;
    }
    for (; j < hi; ++j) {
        int s = eidx[j];
        uint2 v = *reinterpret_cast<const uint2*>(g2 + s * 16 + q * 4);
        float2 p0 = __half22float2(*reinterpret_cast<__half2*>(&v.x));
        float2 p1 = __half22float2(*reinterpret_cast<__half2*>(&v.y));
        a0 += p0.x; a1 += p0.y; a2 += p1.x; a3 += p1.y;
    }
    float di = dinv[d];
    uint2 sv = *reinterpret_cast<const uint2*>(g2 + d * 16 + q * 4);
    float2 sf0 = __half22float2(*reinterpret_cast<__half2*>(&sv.x));
    float2 sf1 = __half22float2(*reinterpret_cast<__half2*>(&sv.y));
    float4 o;
    o.x = di * (a0 + sf0.x);
    o.y = di * (a1 + sf0.y);
    o.z = di * (a2 + sf1.x);
    o.w = di * (a3 + sf1.y);
    *reinterpret_cast<float4*>(agg2 + d * 16 + q * 4) = o;
}

// ---------------- GEMM2: out = agg2 @ W2 + b2 ----------------

__global__ __launch_bounds__(256) void gemm2_kernel(const float* __restrict__ aggin,
                                                    const float* __restrict__ W2,
                                                    const float* __restrict__ b2,
                                                    float* __restrict__ out, int N) {
    __shared__ float sW[16 * 128];
    int t = threadIdx.x;
    for (int i = t; i < 2048; i += 256) sW[i] = W2[i];
    __syncthreads();
    int col = t & 127;
    int half = t >> 7;
    int row0 = blockIdx.x * 16 + half * 8;
    float bias = b2[col];
#pragma unroll
    for (int j = 0; j < 8; ++j) {
        int row = row0 + j;
        if (row >= N) return;
        float acc = bias;
#pragma unroll
        for (int k = 0; k < 16; ++k) acc += aggin[row * 16 + k] * sW[k * 128 + col];
        out[row * 128 + col] = acc;
    }
}

// ---------------- launch ----------------

extern "C" void kernel_launch(void* const* d_in, const int* in_sizes, int n_in,
                              void* d_out, int out_size, void* d_ws, size_t ws_size,
                              hipStream_t stream) {
    const float* x  = (const float*)d_in[0];
    const int*   ei = (const int*)d_in[1];
    const float* W1 = (const float*)d_in[2];
    const float* b1 = (const float*)d_in[3];
    const float* W2 = (const float*)d_in[4];
    const float* b2 = (const float*)d_in[5];
    float* out = (float*)d_out;

    const int N = in_sizes[0] / 128;
    const int E = in_sizes[1] / 2;
    const int* src = ei;
    const int* dst = ei + E;
    const int NB = (N + RANGE - 1) / RANGE;

    // ws (4B units): [pairbuf NB*CAP][gcursor NB][bbase NB+1][rowptr N+1][eidx E][dinv N][agg2 16N][g1 8N][g2 8N]
    unsigned* pairbuf = (unsigned*)d_ws;
    int* gcursor = (int*)(pairbuf + (size_t)NB * CAP);
    int* bbase   = gcursor + NB;
    int* rowptr  = bbase + (NB + 1);
    int* eidx    = rowptr + (N + 1);
    float* dinv  = (float*)(eidx + E);
    float* agg2  = dinv + N;
    __half* g1 = (__half*)(agg2 + 16 * N);
    __half* g2 = g1 + 16 * N;

    const int B = 256;
    init_gcursor<<<1, B, 0, stream>>>(gcursor, NB);
    binpass<<<(E + T_TILE - 1) / T_TILE, B, 0, stream>>>(src, dst, E, gcursor, pairbuf);
    bucketscan<<<1, B, 0, stream>>>(gcursor, NB, bbase, rowptr, N);
    bucket_build<<<NB, 512, 0, stream>>>(pairbuf, gcursor, bbase, N, rowptr, dinv, eidx);
    gemm1_kernel<<<(N + 15) / 16, B, 0, stream>>>(x, W1, dinv, g1, N);
    gather1_kernel<<<(N * 4 + B - 1) / B, B, 0, stream>>>(rowptr, eidx, g1, dinv, b1, g2, N);
    gather2_kernel<<<(N * 4 + B - 1) / B, B, 0, stream>>>(rowptr, eidx, g2, dinv, agg2, N);
    gemm2_kernel<<<(N + 15) / 16, B, 0, stream>>>(agg2, W2, b2, out, N);
}

// Round 9
// 178.928 us; speedup vs baseline: 4.4006x; 1.0901x over previous
//
#include <hip/hip_runtime.h>
#include <hip/hip_fp16.h>

typedef _Float16 half8 __attribute__((ext_vector_type(8)));
typedef float f32x4 __attribute__((ext_vector_type(4)));

// ---------- binned CSR build ----------
#define RANGE    512
#define RSH      9
#define CAP      17408          // mean E/NB=16327 + 8 sigma
#define T_TILE   4096           // edges per binpass block (256 thr x 16)

__global__ void init_gcursor(int* __restrict__ gcursor, int NB) {
    int t = blockIdx.x * blockDim.x + threadIdx.x;
    if (t < NB) gcursor[t] = t * CAP;
}

__global__ __launch_bounds__(256) void binpass(const int* __restrict__ src,
                                               const int* __restrict__ dst, int E,
                                               int* __restrict__ gcursor,
                                               unsigned* __restrict__ pairbuf) {
    __shared__ unsigned sbuf[T_TILE];
    __shared__ unsigned char sbk[T_TILE];
    __shared__ int lcount[256], loff[256], lplace[256], gbase[256];
    int t = threadIdx.x;
    int base = blockIdx.x * T_TILE;
    int ecount = min(T_TILE, E - base);

    lcount[t] = 0;
    __syncthreads();

    unsigned pk[16];
    int bn[16];
#pragma unroll
    for (int k = 0; k < 16; ++k) {
        int i = base + t + k * 256;
        if (i < E) {
            int s = src[i], d = dst[i];
            bn[k] = d >> RSH;
            pk[k] = ((unsigned)s << RSH) | (unsigned)(d & (RANGE - 1));
            atomicAdd(&lcount[bn[k]], 1);
        } else bn[k] = -1;
    }
    __syncthreads();
    loff[t] = lcount[t];
    __syncthreads();
    for (int off = 1; off < 256; off <<= 1) {
        int u = (t >= off) ? loff[t - off] : 0;
        __syncthreads();
        loff[t] += u;
        __syncthreads();
    }
    int ex = loff[t] - lcount[t];
    __syncthreads();
    loff[t] = ex;
    lplace[t] = ex;
    if (lcount[t] > 0) gbase[t] = atomicAdd(&gcursor[t], lcount[t]);
    __syncthreads();
#pragma unroll
    for (int k = 0; k < 16; ++k) {
        if (bn[k] >= 0) {
            int pos = atomicAdd(&lplace[bn[k]], 1);
            sbuf[pos] = pk[k];
            sbk[pos] = (unsigned char)bn[k];
        }
    }
    __syncthreads();
    for (int i = t; i < ecount; i += 256) {
        int b = sbk[i];
        pairbuf[gbase[b] + (i - loff[b])] = sbuf[i];
    }
}

__global__ __launch_bounds__(256) void bucketscan(const int* __restrict__ gcursor, int NB,
                                                  int* __restrict__ bbase,
                                                  int* __restrict__ rowptr, int N) {
    __shared__ int sd[256];
    int t = threadIdx.x;
    int c = (t < NB) ? (gcursor[t] - t * CAP) : 0;
    sd[t] = c;
    __syncthreads();
    for (int off = 1; off < 256; off <<= 1) {
        int u = (t >= off) ? sd[t - off] : 0;
        __syncthreads();
        sd[t] += u;
        __syncthreads();
    }
    if (t < NB) bbase[t] = sd[t] - c;
    if (t == 255) { bbase[NB] = sd[255]; rowptr[N] = sd[255]; }
}

__global__ __launch_bounds__(512) void bucket_build(const unsigned* __restrict__ pairbuf,
                                                    const int* __restrict__ gcursor,
                                                    const int* __restrict__ bbase, int N,
                                                    int* __restrict__ rowptr,
                                                    float* __restrict__ dinv,
                                                    int* __restrict__ eidx) {
    __shared__ int lcnt[RANGE];
    __shared__ int lsc[RANGE];
    int b = blockIdx.x, t = threadIdx.x;
    int cnt = gcursor[b] - b * CAP;
    const unsigned* pb = pairbuf + (size_t)b * CAP;

    lcnt[t] = 0;
    __syncthreads();
    for (int i = t; i < cnt; i += 512) atomicAdd(&lcnt[pb[i] & (RANGE - 1)], 1);
    __syncthreads();
    lsc[t] = lcnt[t];
    __syncthreads();
    for (int off = 1; off < 512; off <<= 1) {
        int u = (t >= off) ? lsc[t - off] : 0;
        __syncthreads();
        lsc[t] += u;
        __syncthreads();
    }
    int ex = lsc[t] - lcnt[t];
    int gb = bbase[b];
    int node = b * RANGE + t;
    if (node < N) {
        rowptr[node] = gb + ex;
        dinv[node] = rsqrtf((float)lcnt[t] + 1.0f);
    }
    __syncthreads();
    lsc[t] = gb + ex;
    __syncthreads();
    for (int i = t; i < cnt; i += 512) {
        unsigned p = pb[i];
        int pos = atomicAdd(&lsc[p & (RANGE - 1)], 1);
        eidx[pos] = (int)(p >> RSH);
    }
}

// ---------------- GEMM1 via MFMA: g1 = fp16((x @ W1) * dinv[row]) ----------------
// wave = 16 rows x 16 cols, K=128 = 4 x mfma_f32_16x16x32_f16. No LDS.
// A: lane l holds x[R0+(l&15)][kb..kb+7], kb=(l>>4)*8 (+kk*32)
// B: lane l holds W1[kb+j][l&15]
// D: lane l holds out[R0+(l>>4)*4+i][l&15]

__global__ __launch_bounds__(256) void gemm1_mfma(const float* __restrict__ x,
                                                  const float* __restrict__ W1,
                                                  const float* __restrict__ dinv,
                                                  __half* __restrict__ g1, int N) {
    int wave = threadIdx.x >> 6;
    int lane = threadIdx.x & 63;
    int R0 = blockIdx.x * 64 + wave * 16;
    if (R0 >= N) return;                 // wave-uniform
    int m = lane & 15;
    int kb = (lane >> 4) * 8;
    int row = R0 + m;
    int rowc = min(row, N - 1);

    // B fragments (L2-hit scalar loads, once per wave)
    half8 bfrag[4];
#pragma unroll
    for (int kk = 0; kk < 4; ++kk) {
#pragma unroll
        for (int j = 0; j < 8; ++j)
            bfrag[kk][j] = (_Float16)W1[(kk * 32 + kb + j) * 16 + m];
    }

    const float* xr = x + (size_t)rowc * 128;
    float4 u[8];
#pragma unroll
    for (int kk = 0; kk < 4; ++kk) {
        u[2 * kk]     = *reinterpret_cast<const float4*>(xr + kk * 32 + kb);
        u[2 * kk + 1] = *reinterpret_cast<const float4*>(xr + kk * 32 + kb + 4);
    }

    f32x4 acc = {0.f, 0.f, 0.f, 0.f};
#pragma unroll
    for (int kk = 0; kk < 4; ++kk) {
        half8 a;
        a[0] = (_Float16)u[2 * kk].x;     a[1] = (_Float16)u[2 * kk].y;
        a[2] = (_Float16)u[2 * kk].z;     a[3] = (_Float16)u[2 * kk].w;
        a[4] = (_Float16)u[2 * kk + 1].x; a[5] = (_Float16)u[2 * kk + 1].y;
        a[6] = (_Float16)u[2 * kk + 1].z; a[7] = (_Float16)u[2 * kk + 1].w;
        acc = __builtin_amdgcn_mfma_f32_16x16x32_f16(a, bfrag[kk], acc, 0, 0, 0);
    }

#pragma unroll
    for (int i = 0; i < 4; ++i) {
        int r = R0 + (lane >> 4) * 4 + i;
        if (r < N) g1[(size_t)r * 16 + m] = __float2half(acc[i] * dinv[r]);
    }
}

// ---------------- gather1: lane = (node, quarter); 16 consecutive nodes/wave ----------------

__global__ __launch_bounds__(256) void gather1_kernel(const int* __restrict__ rowptr,
                                                      const int* __restrict__ eidx,
                                                      const __half* __restrict__ g1,
                                                      const float* __restrict__ dinv,
                                                      const float* __restrict__ b1,
                                                      __half* __restrict__ g2, int N) {
    int gid = blockIdx.x * blockDim.x + threadIdx.x;
    int lane = threadIdx.x & 63;
    int q = lane & 3;
    int d = gid >> 2;
    if (d >= N) return;
    int lo = rowptr[d], hi = rowptr[d + 1];
    float a0 = 0, a1 = 0, a2 = 0, a3 = 0;
    int j = lo;
    for (; j + 3 < hi; j += 4) {
        int s0 = eidx[j], s1 = eidx[j + 1], s2 = eidx[j + 2], s3 = eidx[j + 3];
        uint2 v0 = *reinterpret_cast<const uint2*>(g1 + s0 * 16 + q * 4);
        uint2 v1 = *reinterpret_cast<const uint2*>(g1 + s1 * 16 + q * 4);
        uint2 v2 = *reinterpret_cast<const uint2*>(g1 + s2 * 16 + q * 4);
        uint2 v3 = *reinterpret_cast<const uint2*>(g1 + s3 * 16 + q * 4);
        float2 p0 = __half22float2(*reinterpret_cast<__half2*>(&v0.x));
        float2 p1 = __half22float2(*reinterpret_cast<__half2*>(&v0.y));
        a0 += p0.x; a1 += p0.y; a2 += p1.x; a3 += p1.y;
        p0 = __half22float2(*reinterpret_cast<__half2*>(&v1.x));
        p1 = __half22float2(*reinterpret_cast<__half2*>(&v1.y));
        a0 += p0.x; a1 += p0.y; a2 += p1.x; a3 += p1.y;
        p0 = __half22float2(*reinterpret_cast<__half2*>(&v2.x));
        p1 = __half22float2(*reinterpret_cast<__half2*>(&v2.y));
        a0 += p0.x; a1 += p0.y; a2 += p1.x; a3 += p1.y;
        p0 = __half22float2(*reinterpret_cast<__half2*>(&v3.x));
        p1 = __half22float2(*reinterpret_cast<__half2*>(&v3.y));
        a0 += p0.x; a1 += p0.y; a2 += p1.x; a3 += p1.y;
    }
    for (; j < hi; ++j) {
        int s = eidx[j];
        uint2 v = *reinterpret_cast<const uint2*>(g1 + s * 16 + q * 4);
        float2 p0 = __half22float2(*reinterpret_cast<__half2*>(&v.x));
        float2 p1 = __half22float2(*reinterpret_cast<__half2*>(&v.y));
        a0 += p0.x; a1 += p0.y; a2 += p1.x; a3 += p1.y;
    }
    float di = dinv[d];
    uint2 sv = *reinterpret_cast<const uint2*>(g1 + d * 16 + q * 4);
    float2 sf0 = __half22float2(*reinterpret_cast<__half2*>(&sv.x));
    float2 sf1 = __half22float2(*reinterpret_cast<__half2*>(&sv.y));
    float4 bb = *reinterpret_cast<const float4*>(b1 + q * 4);
    float o0 = fmaxf(di * (a0 + sf0.x) + bb.x, 0.0f) * di;
    float o1 = fmaxf(di * (a1 + sf0.y) + bb.y, 0.0f) * di;
    float o2 = fmaxf(di * (a2 + sf1.x) + bb.z, 0.0f) * di;
    float o3 = fmaxf(di * (a3 + sf1.y) + bb.w, 0.0f) * di;
    __half2 w0 = __floats2half2_rn(o0, o1);
    __half2 w1 = __floats2half2_rn(o2, o3);
    uint2 wv;
    wv.x = *reinterpret_cast<unsigned*>(&w0);
    wv.y = *reinterpret_cast<unsigned*>(&w1);
    *reinterpret_cast<uint2*>(g2 + d * 16 + q * 4) = wv;
}

// ---------------- gather2: same structure, fp32 out ----------------

__global__ __launch_bounds__(256) void gather2_kernel(const int* __restrict__ rowptr,
                                                      const int* __restrict__ eidx,
                                                      const __half* __restrict__ g2,
                                                      const float* __restrict__ dinv,
                                                      float* __restrict__ agg2, int N) {
    int gid = blockIdx.x * blockDim.x + threadIdx.x;
    int lane = threadIdx.x & 63;
    int q = lane & 3;
    int d = gid >> 2;
    if (d >= N) return;
    int lo = rowptr[d], hi = rowptr[d + 1];
    float a0 = 0, a1 = 0, a2 = 0, a3 = 0;
    int j = lo;
    for (; j + 3 < hi; j += 4) {
        int s0 = eidx[j], s1 = eidx[j + 1], s2 = eidx[j + 2], s3 = eidx[j + 3];
        uint2 v0 = *reinterpret_cast<const uint2*>(g2 + s0 * 16 + q * 4);
        uint2 v1 = *reinterpret_cast<const uint2*>(g2 + s1 * 16 + q * 4);
        uint2 v2 = *reinterpret_cast<const uint2*>(g2 + s2 * 16 + q * 4);
        uint2 v3 = *reinterpret_cast<const uint2*>(g2 + s3 * 16 + q * 4);
        float2 p0 = __half22float2(*reinterpret_cast<__half2*>(&v0.x));
        float2 p1 = __half22float2(*reinterpret_cast<__half2*>(&v0.y));
        a0 += p0.x; a1 += p0.y; a2 += p1.x; a3 += p1.y;
        p0 = __half22float2(*reinterpret_cast<__half2*>(&v1.x));
        p1 = __half22float2(*reinterpret_cast<__half2*>(&v1.y));
        a0 += p0.x; a1 += p0.y; a2 += p1.x; a3 += p1.y;
        p0 = __half22float2(*reinterpret_cast<__half2*>(&v2.x));
        p1 = __half22float2(*reinterpret_cast<__half2*>(&v2.y));
        a0 += p0.x; a1 += p0.y; a2 += p1.x; a3 += p1.y;
        p0 = __half22float2(*reinterpret_cast<__half2*>(&v3.x));
        p1 = __half22float2(*reinterpret_cast<__half2*>(&v3.y));
        a0 += p0.x; a1 += p0.y; a2 += p1.x; a3 += p1.y;
    }
    for (; j < hi; ++j) {
        int s = eidx[j];
        uint2 v = *reinterpret_cast<const uint2*>(g2 + s * 16 + q * 4);
        float2 p0 = __half22float2(*reinterpret_cast<__half2*>(&v.x));
        float2 p1 = __half22float2(*reinterpret_cast<__half2*>(&v.y));
        a0 += p0.x; a1 += p0.y; a2 += p1.x; a3 += p1.y;
    }
    float di = dinv[d];
    uint2 sv = *reinterpret_cast<const uint2*>(g2 + d * 16 + q * 4);
    float2 sf0 = __half22float2(*reinterpret_cast<__half2*>(&sv.x));
    float2 sf1 = __half22float2(*reinterpret_cast<__half2*>(&sv.y));
    float4 o;
    o.x = di * (a0 + sf0.x);
    o.y = di * (a1 + sf0.y);
    o.z = di * (a2 + sf1.x);
    o.w = di * (a3 + sf1.y);
    *reinterpret_cast<float4*>(agg2 + d * 16 + q * 4) = o;
}

// ---------------- GEMM2: out = agg2 @ W2 + b2 ----------------

__global__ __launch_bounds__(256) void gemm2_kernel(const float* __restrict__ aggin,
                                                    const float* __restrict__ W2,
                                                    const float* __restrict__ b2,
                                                    float* __restrict__ out, int N) {
    __shared__ float sW[16 * 128];
    int t = threadIdx.x;
    for (int i = t; i < 2048; i += 256) sW[i] = W2[i];
    __syncthreads();
    int col = t & 127;
    int half = t >> 7;
    int row0 = blockIdx.x * 16 + half * 8;
    float bias = b2[col];
#pragma unroll
    for (int j = 0; j < 8; ++j) {
        int row = row0 + j;
        if (row >= N) return;
        float acc = bias;
#pragma unroll
        for (int k = 0; k < 16; ++k) acc += aggin[row * 16 + k] * sW[k * 128 + col];
        out[row * 128 + col] = acc;
    }
}

// ---------------- launch ----------------

extern "C" void kernel_launch(void* const* d_in, const int* in_sizes, int n_in,
                              void* d_out, int out_size, void* d_ws, size_t ws_size,
                              hipStream_t stream) {
    const float* x  = (const float*)d_in[0];
    const int*   ei = (const int*)d_in[1];
    const float* W1 = (const float*)d_in[2];
    const float* b1 = (const float*)d_in[3];
    const float* W2 = (const float*)d_in[4];
    const float* b2 = (const float*)d_in[5];
    float* out = (float*)d_out;

    const int N = in_sizes[0] / 128;
    const int E = in_sizes[1] / 2;
    const int* src = ei;
    const int* dst = ei + E;
    const int NB = (N + RANGE - 1) / RANGE;

    // ws (4B units): [pairbuf NB*CAP][gcursor NB][bbase NB+1][rowptr N+1][eidx E][dinv N][agg2 16N][g1 8N][g2 8N]
    unsigned* pairbuf = (unsigned*)d_ws;
    int* gcursor = (int*)(pairbuf + (size_t)NB * CAP);
    int* bbase   = gcursor + NB;
    int* rowptr  = bbase + (NB + 1);
    int* eidx    = rowptr + (N + 1);
    float* dinv  = (float*)(eidx + E);
    float* agg2  = dinv + N;
    __half* g1 = (__half*)(agg2 + 16 * N);
    __half* g2 = g1 + 16 * N;

    const int B = 256;
    init_gcursor<<<1, B, 0, stream>>>(gcursor, NB);
    binpass<<<(E + T_TILE - 1) / T_TILE, B, 0, stream>>>(src, dst, E, gcursor, pairbuf);
    bucketscan<<<1, B, 0, stream>>>(gcursor, NB, bbase, rowptr, N);
    bucket_build<<<NB, 512, 0, stream>>>(pairbuf, gcursor, bbase, N, rowptr, dinv, eidx);
    gemm1_mfma<<<(N + 63) / 64, B, 0, stream>>>(x, W1, dinv, g1, N);
    gather1_kernel<<<(N * 4 + B - 1) / B, B, 0, stream>>>(rowptr, eidx, g1, dinv, b1, g2, N);
    gather2_kernel<<<(N * 4 + B - 1) / B, B, 0, stream>>>(rowptr, eidx, g2, dinv, agg2, N);
    gemm2_kernel<<<(N + 15) / 16, B, 0, stream>>>(agg2, W2, b2, out, N);
}

// Round 10
// 157.167 us; speedup vs baseline: 5.0099x; 1.1385x over previous
//
#include <hip/hip_runtime.h>
#include <hip/hip_fp16.h>

typedef _Float16 half8 __attribute__((ext_vector_type(8)));
typedef _Float16 half4 __attribute__((ext_vector_type(4)));
typedef float f32x4 __attribute__((ext_vector_type(4)));

// ---------- binned CSR build ----------
#define RANGE    512
#define RSH      9
#define CAP      17408          // mean E/NB=16327 + 8 sigma
#define T_TILE   4096           // edges per binpass block (256 thr x 16)

__global__ void init_gcursor(int* __restrict__ gcursor, int NB) {
    int t = blockIdx.x * blockDim.x + threadIdx.x;
    if (t < NB) gcursor[t] = t * CAP;
}

__global__ __launch_bounds__(256) void binpass(const int* __restrict__ src,
                                               const int* __restrict__ dst, int E,
                                               int* __restrict__ gcursor,
                                               unsigned* __restrict__ pairbuf) {
    __shared__ unsigned sbuf[T_TILE];
    __shared__ unsigned char sbk[T_TILE];
    __shared__ int lcount[256], loff[256], lplace[256], gbase[256];
    int t = threadIdx.x;
    int base = blockIdx.x * T_TILE;
    int ecount = min(T_TILE, E - base);

    lcount[t] = 0;
    __syncthreads();

    unsigned pk[16];
    int bn[16];
#pragma unroll
    for (int k = 0; k < 16; ++k) {
        int i = base + t + k * 256;
        if (i < E) {
            int s = src[i], d = dst[i];
            bn[k] = d >> RSH;
            pk[k] = ((unsigned)s << RSH) | (unsigned)(d & (RANGE - 1));
            atomicAdd(&lcount[bn[k]], 1);
        } else bn[k] = -1;
    }
    __syncthreads();
    loff[t] = lcount[t];
    __syncthreads();
    for (int off = 1; off < 256; off <<= 1) {
        int u = (t >= off) ? loff[t - off] : 0;
        __syncthreads();
        loff[t] += u;
        __syncthreads();
    }
    int ex = loff[t] - lcount[t];
    __syncthreads();
    loff[t] = ex;
    lplace[t] = ex;
    if (lcount[t] > 0) gbase[t] = atomicAdd(&gcursor[t], lcount[t]);
    __syncthreads();
#pragma unroll
    for (int k = 0; k < 16; ++k) {
        if (bn[k] >= 0) {
            int pos = atomicAdd(&lplace[bn[k]], 1);
            sbuf[pos] = pk[k];
            sbk[pos] = (unsigned char)bn[k];
        }
    }
    __syncthreads();
    for (int i = t; i < ecount; i += 256) {
        int b = sbk[i];
        pairbuf[gbase[b] + (i - loff[b])] = sbuf[i];
    }
}

__global__ __launch_bounds__(256) void bucketscan(const int* __restrict__ gcursor, int NB,
                                                  int* __restrict__ bbase,
                                                  int* __restrict__ rowptr, int N) {
    __shared__ int sd[256];
    int t = threadIdx.x;
    int c = (t < NB) ? (gcursor[t] - t * CAP) : 0;
    sd[t] = c;
    __syncthreads();
    for (int off = 1; off < 256; off <<= 1) {
        int u = (t >= off) ? sd[t - off] : 0;
        __syncthreads();
        sd[t] += u;
        __syncthreads();
    }
    if (t < NB) bbase[t] = sd[t] - c;
    if (t == 255) { bbase[NB] = sd[255]; rowptr[N] = sd[255]; }
}

__global__ __launch_bounds__(512) void bucket_build(const unsigned* __restrict__ pairbuf,
                                                    const int* __restrict__ gcursor,
                                                    const int* __restrict__ bbase, int N,
                                                    int* __restrict__ rowptr,
                                                    float* __restrict__ dinv,
                                                    int* __restrict__ eidx) {
    __shared__ int lcnt[RANGE];
    __shared__ int lsc[RANGE];
    int b = blockIdx.x, t = threadIdx.x;
    int cnt = gcursor[b] - b * CAP;
    const unsigned* pb = pairbuf + (size_t)b * CAP;

    lcnt[t] = 0;
    __syncthreads();
    for (int i = t; i < cnt; i += 512) atomicAdd(&lcnt[pb[i] & (RANGE - 1)], 1);
    __syncthreads();
    lsc[t] = lcnt[t];
    __syncthreads();
    for (int off = 1; off < 512; off <<= 1) {
        int u = (t >= off) ? lsc[t - off] : 0;
        __syncthreads();
        lsc[t] += u;
        __syncthreads();
    }
    int ex = lsc[t] - lcnt[t];
    int gb = bbase[b];
    int node = b * RANGE + t;
    if (node < N) {
        rowptr[node] = gb + ex;
        dinv[node] = rsqrtf((float)lcnt[t] + 1.0f);
    }
    __syncthreads();
    lsc[t] = gb + ex;
    __syncthreads();
    for (int i = t; i < cnt; i += 512) {
        unsigned p = pb[i];
        int pos = atomicAdd(&lsc[p & (RANGE - 1)], 1);
        eidx[pos] = (int)(p >> RSH);
    }
}

// ---------------- GEMM1 via MFMA: g1 = fp16((x @ W1) * dinv[row]) ----------------

__global__ __launch_bounds__(256) void gemm1_mfma(const float* __restrict__ x,
                                                  const float* __restrict__ W1,
                                                  const float* __restrict__ dinv,
                                                  __half* __restrict__ g1, int N) {
    int wave = threadIdx.x >> 6;
    int lane = threadIdx.x & 63;
    int R0 = blockIdx.x * 64 + wave * 16;
    if (R0 >= N) return;
    int m = lane & 15;
    int kb = (lane >> 4) * 8;
    int row = R0 + m;
    int rowc = min(row, N - 1);

    half8 bfrag[4];
#pragma unroll
    for (int kk = 0; kk < 4; ++kk) {
#pragma unroll
        for (int j = 0; j < 8; ++j)
            bfrag[kk][j] = (_Float16)W1[(kk * 32 + kb + j) * 16 + m];
    }

    const float* xr = x + (size_t)rowc * 128;
    float4 u[8];
#pragma unroll
    for (int kk = 0; kk < 4; ++kk) {
        u[2 * kk]     = *reinterpret_cast<const float4*>(xr + kk * 32 + kb);
        u[2 * kk + 1] = *reinterpret_cast<const float4*>(xr + kk * 32 + kb + 4);
    }

    f32x4 acc = {0.f, 0.f, 0.f, 0.f};
#pragma unroll
    for (int kk = 0; kk < 4; ++kk) {
        half8 a;
        a[0] = (_Float16)u[2 * kk].x;     a[1] = (_Float16)u[2 * kk].y;
        a[2] = (_Float16)u[2 * kk].z;     a[3] = (_Float16)u[2 * kk].w;
        a[4] = (_Float16)u[2 * kk + 1].x; a[5] = (_Float16)u[2 * kk + 1].y;
        a[6] = (_Float16)u[2 * kk + 1].z; a[7] = (_Float16)u[2 * kk + 1].w;
        acc = __builtin_amdgcn_mfma_f32_16x16x32_f16(a, bfrag[kk], acc, 0, 0, 0);
    }

#pragma unroll
    for (int i = 0; i < 4; ++i) {
        int r = R0 + (lane >> 4) * 4 + i;
        if (r < N) g1[(size_t)r * 16 + m] = __float2half(acc[i] * dinv[r]);
    }
}

// ---------------- gather1: lane = (node, quarter); 16 consecutive nodes/wave ----------------

__global__ __launch_bounds__(256) void gather1_kernel(const int* __restrict__ rowptr,
                                                      const int* __restrict__ eidx,
                                                      const __half* __restrict__ g1,
                                                      const float* __restrict__ dinv,
                                                      const float* __restrict__ b1,
                                                      __half* __restrict__ g2, int N) {
    int gid = blockIdx.x * blockDim.x + threadIdx.x;
    int lane = threadIdx.x & 63;
    int q = lane & 3;
    int d = gid >> 2;
    if (d >= N) return;
    int lo = rowptr[d], hi = rowptr[d + 1];
    float a0 = 0, a1 = 0, a2 = 0, a3 = 0;
    int j = lo;
    for (; j + 3 < hi; j += 4) {
        int s0 = eidx[j], s1 = eidx[j + 1], s2 = eidx[j + 2], s3 = eidx[j + 3];
        uint2 v0 = *reinterpret_cast<const uint2*>(g1 + s0 * 16 + q * 4);
        uint2 v1 = *reinterpret_cast<const uint2*>(g1 + s1 * 16 + q * 4);
        uint2 v2 = *reinterpret_cast<const uint2*>(g1 + s2 * 16 + q * 4);
        uint2 v3 = *reinterpret_cast<const uint2*>(g1 + s3 * 16 + q * 4);
        float2 p0 = __half22float2(*reinterpret_cast<__half2*>(&v0.x));
        float2 p1 = __half22float2(*reinterpret_cast<__half2*>(&v0.y));
        a0 += p0.x; a1 += p0.y; a2 += p1.x; a3 += p1.y;
        p0 = __half22float2(*reinterpret_cast<__half2*>(&v1.x));
        p1 = __half22float2(*reinterpret_cast<__half2*>(&v1.y));
        a0 += p0.x; a1 += p0.y; a2 += p1.x; a3 += p1.y;
        p0 = __half22float2(*reinterpret_cast<__half2*>(&v2.x));
        p1 = __half22float2(*reinterpret_cast<__half2*>(&v2.y));
        a0 += p0.x; a1 += p0.y; a2 += p1.x; a3 += p1.y;
        p0 = __half22float2(*reinterpret_cast<__half2*>(&v3.x));
        p1 = __half22float2(*reinterpret_cast<__half2*>(&v3.y));
        a0 += p0.x; a1 += p0.y; a2 += p1.x; a3 += p1.y;
    }
    for (; j < hi; ++j) {
        int s = eidx[j];
        uint2 v = *reinterpret_cast<const uint2*>(g1 + s * 16 + q * 4);
        float2 p0 = __half22float2(*reinterpret_cast<__half2*>(&v.x));
        float2 p1 = __half22float2(*reinterpret_cast<__half2*>(&v.y));
        a0 += p0.x; a1 += p0.y; a2 += p1.x; a3 += p1.y;
    }
    float di = dinv[d];
    uint2 sv = *reinterpret_cast<const uint2*>(g1 + d * 16 + q * 4);
    float2 sf0 = __half22float2(*reinterpret_cast<__half2*>(&sv.x));
    float2 sf1 = __half22float2(*reinterpret_cast<__half2*>(&sv.y));
    float4 bb = *reinterpret_cast<const float4*>(b1 + q * 4);
    float o0 = fmaxf(di * (a0 + sf0.x) + bb.x, 0.0f) * di;
    float o1 = fmaxf(di * (a1 + sf0.y) + bb.y, 0.0f) * di;
    float o2 = fmaxf(di * (a2 + sf1.x) + bb.z, 0.0f) * di;
    float o3 = fmaxf(di * (a3 + sf1.y) + bb.w, 0.0f) * di;
    __half2 w0 = __floats2half2_rn(o0, o1);
    __half2 w1 = __floats2half2_rn(o2, o3);
    uint2 wv;
    wv.x = *reinterpret_cast<unsigned*>(&w0);
    wv.y = *reinterpret_cast<unsigned*>(&w1);
    *reinterpret_cast<uint2*>(g2 + d * 16 + q * 4) = wv;
}

// ---------------- fused gather2 + GEMM2 ----------------
// wave = 16 nodes. Gather role: lane l -> node base+(l&15), feature quarter q=l>>4.
// After accumulation lane l holds A[row=l&15][k=q*4+j] = agg[node][feat] -- exactly the
// mfma_f32_16x16x16_f16 A-fragment. 8 MFMAs (one per 16-col tile of W2) -> out tile.
// D layout: col=lane&15, row=(lane>>4)*4+reg.

__global__ __launch_bounds__(256) void gather2_gemm2(const int* __restrict__ rowptr,
                                                     const int* __restrict__ eidx,
                                                     const __half* __restrict__ g2,
                                                     const float* __restrict__ dinv,
                                                     const float* __restrict__ W2,
                                                     const float* __restrict__ b2,
                                                     float* __restrict__ out, int N) {
    int gid = blockIdx.x * blockDim.x + threadIdx.x;
    int wid = gid >> 6;
    int lane = threadIdx.x & 63;
    int base = wid * 16;
    if (base >= N) return;
    int nl = lane & 15;
    int q = lane >> 4;
    int d = base + nl;
    int dc = min(d, N - 1);
    int lo = rowptr[dc], hi = rowptr[dc + 1];

    float a0 = 0, a1 = 0, a2 = 0, a3 = 0;
    int j = lo;
    for (; j + 3 < hi; j += 4) {
        int s0 = eidx[j], s1 = eidx[j + 1], s2 = eidx[j + 2], s3 = eidx[j + 3];
        uint2 v0 = *reinterpret_cast<const uint2*>(g2 + s0 * 16 + q * 4);
        uint2 v1 = *reinterpret_cast<const uint2*>(g2 + s1 * 16 + q * 4);
        uint2 v2 = *reinterpret_cast<const uint2*>(g2 + s2 * 16 + q * 4);
        uint2 v3 = *reinterpret_cast<const uint2*>(g2 + s3 * 16 + q * 4);
        float2 p0 = __half22float2(*reinterpret_cast<__half2*>(&v0.x));
        float2 p1 = __half22float2(*reinterpret_cast<__half2*>(&v0.y));
        a0 += p0.x; a1 += p0.y; a2 += p1.x; a3 += p1.y;
        p0 = __half22float2(*reinterpret_cast<__half2*>(&v1.x));
        p1 = __half22float2(*reinterpret_cast<__half2*>(&v1.y));
        a0 += p0.x; a1 += p0.y; a2 += p1.x; a3 += p1.y;
        p0 = __half22float2(*reinterpret_cast<__half2*>(&v2.x));
        p1 = __half22float2(*reinterpret_cast<__half2*>(&v2.y));
        a0 += p0.x; a1 += p0.y; a2 += p1.x; a3 += p1.y;
        p0 = __half22float2(*reinterpret_cast<__half2*>(&v3.x));
        p1 = __half22float2(*reinterpret_cast<__half2*>(&v3.y));
        a0 += p0.x; a1 += p0.y; a2 += p1.x; a3 += p1.y;
    }
    for (; j < hi; ++j) {
        int s = eidx[j];
        uint2 v = *reinterpret_cast<const uint2*>(g2 + s * 16 + q * 4);
        float2 p0 = __half22float2(*reinterpret_cast<__half2*>(&v.x));
        float2 p1 = __half22float2(*reinterpret_cast<__half2*>(&v.y));
        a0 += p0.x; a1 += p0.y; a2 += p1.x; a3 += p1.y;
    }

    // self-loop + dinv -> A fragment (fp16)
    float di = dinv[dc];
    uint2 sv = *reinterpret_cast<const uint2*>(g2 + dc * 16 + q * 4);
    float2 sf0 = __half22float2(*reinterpret_cast<__half2*>(&sv.x));
    float2 sf1 = __half22float2(*reinterpret_cast<__half2*>(&sv.y));
    half4 afrag;
    afrag[0] = (_Float16)(di * (a0 + sf0.x));
    afrag[1] = (_Float16)(di * (a1 + sf0.y));
    afrag[2] = (_Float16)(di * (a2 + sf1.x));
    afrag[3] = (_Float16)(di * (a3 + sf1.y));

    // 8 MFMAs over W2 column tiles
    f32x4 dacc[8];
#pragma unroll
    for (int ct = 0; ct < 8; ++ct) {
        half4 bfrag;
#pragma unroll
        for (int jj = 0; jj < 4; ++jj)
            bfrag[jj] = (_Float16)W2[(q * 4 + jj) * 128 + ct * 16 + nl];
        f32x4 z = {0.f, 0.f, 0.f, 0.f};
        dacc[ct] = __builtin_amdgcn_mfma_f32_16x16x16f16(afrag, bfrag, z, 0, 0, 0);
    }

    float bias[8];
#pragma unroll
    for (int ct = 0; ct < 8; ++ct) bias[ct] = b2[ct * 16 + nl];

    int rbase = base + q * 4;
#pragma unroll
    for (int i = 0; i < 4; ++i) {
        int r = rbase + i;
        if (r < N) {
            float* orow = out + (size_t)r * 128 + nl;
#pragma unroll
            for (int ct = 0; ct < 8; ++ct) orow[ct * 16] = dacc[ct][i] + bias[ct];
        }
    }
}

// ---------------- launch ----------------

extern "C" void kernel_launch(void* const* d_in, const int* in_sizes, int n_in,
                              void* d_out, int out_size, void* d_ws, size_t ws_size,
                              hipStream_t stream) {
    const float* x  = (const float*)d_in[0];
    const int*   ei = (const int*)d_in[1];
    const float* W1 = (const float*)d_in[2];
    const float* b1 = (const float*)d_in[3];
    const float* W2 = (const float*)d_in[4];
    const float* b2 = (const float*)d_in[5];
    float* out = (float*)d_out;

    const int N = in_sizes[0] / 128;
    const int E = in_sizes[1] / 2;
    const int* src = ei;
    const int* dst = ei + E;
    const int NB = (N + RANGE - 1) / RANGE;

    // ws (4B units): [pairbuf NB*CAP][gcursor NB][bbase NB+1][rowptr N+1][eidx E][dinv N][g1 8N][g2 8N]
    unsigned* pairbuf = (unsigned*)d_ws;
    int* gcursor = (int*)(pairbuf + (size_t)NB * CAP);
    int* bbase   = gcursor + NB;
    int* rowptr  = bbase + (NB + 1);
    int* eidx    = rowptr + (N + 1);
    float* dinv  = (float*)(eidx + E);
    __half* g1 = (__half*)(dinv + N);
    __half* g2 = g1 + 16 * N;

    const int B = 256;
    init_gcursor<<<1, B, 0, stream>>>(gcursor, NB);
    binpass<<<(E + T_TILE - 1) / T_TILE, B, 0, stream>>>(src, dst, E, gcursor, pairbuf);
    bucketscan<<<1, B, 0, stream>>>(gcursor, NB, bbase, rowptr, N);
    bucket_build<<<NB, 512, 0, stream>>>(pairbuf, gcursor, bbase, N, rowptr, dinv, eidx);
    gemm1_mfma<<<(N + 63) / 64, B, 0, stream>>>(x, W1, dinv, g1, N);
    gather1_kernel<<<(N * 4 + B - 1) / B, B, 0, stream>>>(rowptr, eidx, g1, dinv, b1, g2, N);
    gather2_gemm2<<<(N * 4 + B - 1) / B, B, 0, stream>>>(rowptr, eidx, g2, dinv, W2, b2, out, N);
}